// Round 1
// baseline (499.307 us; speedup 1.0000x reference)
//
#include <hip/hip_runtime.h>
#include <math.h>

#define N_LEVELS 14

// One thread per point. All weight accesses are wave-uniform -> expect s_load
// scalarization. Register arrays in[36]/acc[64] are only ever indexed with
// compile-time constants (loops fully unrolled where they index them).
__global__ __launch_bounds__(256) void deformnet_kernel(
    const float* __restrict__ x,
    const float* __restrict__ e,
    const float* __restrict__ tables,
    const float* __restrict__ W1,
    const float* __restrict__ b1,
    const float* __restrict__ W2,
    const float* __restrict__ b2,
    const float* __restrict__ W3,
    const float* __restrict__ b3,
    const float* __restrict__ bb,
    float* __restrict__ out,
    int N)
{
    const int n = blockIdx.x * blockDim.x + threadIdx.x;
    if (n >= N) return;

    const float lo0 = bb[0], lo1 = bb[1], lo2 = bb[2];
    const float s0 = bb[3] - lo0, s1 = bb[4] - lo1, s2 = bb[5] - lo2;
    const float xn0 = (x[3*n+0] - lo0) / s0;
    const float xn1 = (x[3*n+1] - lo1) / s1;
    const float xn2 = (x[3*n+2] - lo2) / s2;

    float in[36];

    // floor(16 * 1.32^l) for l in 0..13
    const int RES[N_LEVELS] = {16,21,27,36,48,64,84,111,147,194,256,339,447,590};

    #pragma unroll
    for (int l = 0; l < N_LEVELS; ++l) {
        const float r = (float)RES[l];
        float px = xn0*r, py = xn1*r, pz = xn2*r;
        float bxf = floorf(px), byf = floorf(py), bzf = floorf(pz);
        float fx = px-bxf, fy = py-byf, fz = pz-bzf;
        // smoothstep weights
        float wx = fx*fx*(3.0f-2.0f*fx);
        float wy = fy*fy*(3.0f-2.0f*fy);
        float wz = fz*fz*(3.0f-2.0f*fz);
        unsigned bx = (unsigned)bxf, by = (unsigned)byf, bz = (unsigned)bzf;
        unsigned hx0 = bx,                 hx1 = bx + 1u;
        unsigned hy0 = by * 2654435761u,   hy1 = (by+1u) * 2654435761u;
        unsigned hz0 = bz * 805459861u,    hz1 = (bz+1u) * 805459861u;
        const float* tb = tables + (size_t)l * (size_t)((1u<<19) * 2u);
        float wx0 = 1.0f-wx, wy0 = 1.0f-wy, wz0 = 1.0f-wz;
        float f0 = 0.0f, f1 = 0.0f;

        #define CORNER(HX,HY,HZ,WW) { \
            unsigned h_ = ((HX) ^ (HY) ^ (HZ)) & 0x7FFFFu; \
            const float2 t_ = *(const float2*)(tb + 2u*h_); \
            float w_ = (WW); \
            f0 += w_ * t_.x; f1 += w_ * t_.y; }

        CORNER(hx0, hy0, hz0, wx0*wy0*wz0);
        CORNER(hx0, hy0, hz1, wx0*wy0*wz );
        CORNER(hx0, hy1, hz0, wx0*wy *wz0);
        CORNER(hx0, hy1, hz1, wx0*wy *wz );
        CORNER(hx1, hy0, hz0, wx *wy0*wz0);
        CORNER(hx1, hy0, hz1, wx *wy0*wz );
        CORNER(hx1, hy1, hz0, wx *wy *wz0);
        CORNER(hx1, hy1, hz1, wx *wy *wz );
        #undef CORNER

        in[2*l+0] = f0;
        in[2*l+1] = f1;
    }

    {
        const float4 e0 = *(const float4*)(e + 8*(size_t)n);
        const float4 e1 = *(const float4*)(e + 8*(size_t)n + 4);
        in[28]=e0.x; in[29]=e0.y; in[30]=e0.z; in[31]=e0.w;
        in[32]=e1.x; in[33]=e1.y; in[34]=e1.z; in[35]=e1.w;
    }

    // Layer 2 accumulators (h2 pre-activation), rank-1 updated as each h1[j]
    // is produced -> h1 never stored as an array.
    float acc[64];
    #pragma unroll
    for (int k = 0; k < 64; ++k) acc[k] = b2[k];

    #pragma unroll 4
    for (int j = 0; j < 64; ++j) {
        float a = b1[j];
        #pragma unroll
        for (int i = 0; i < 36; ++i) a += in[i] * W1[i*64 + j];
        float h = tanhf(a);
        const float* w2r = W2 + j*64;
        #pragma unroll
        for (int k = 0; k < 64; ++k) acc[k] += h * w2r[k];
    }

    // Layer 3 (64 -> 3), fused with h2 tanh. Fully unrolled so acc[j] stays
    // in registers.
    float o0 = b3[0], o1 = b3[1], o2 = b3[2];
    #pragma unroll
    for (int j = 0; j < 64; ++j) {
        float h = tanhf(acc[j]);
        o0 += h * W3[3*j+0];
        o1 += h * W3[3*j+1];
        o2 += h * W3[3*j+2];
    }

    out[3*n+0] = (o0 + xn0) * s0 + lo0;
    out[3*n+1] = (o1 + xn1) * s1 + lo1;
    out[3*n+2] = (o2 + xn2) * s2 + lo2;
}

extern "C" void kernel_launch(void* const* d_in, const int* in_sizes, int n_in,
                              void* d_out, int out_size, void* d_ws, size_t ws_size,
                              hipStream_t stream) {
    const float* x      = (const float*)d_in[0];
    const float* e      = (const float*)d_in[1];
    const float* tables = (const float*)d_in[2];
    const float* W1     = (const float*)d_in[3];
    const float* b1     = (const float*)d_in[4];
    const float* W2     = (const float*)d_in[5];
    const float* b2     = (const float*)d_in[6];
    const float* W3     = (const float*)d_in[7];
    const float* b3     = (const float*)d_in[8];
    const float* bb     = (const float*)d_in[9];
    float* out = (float*)d_out;

    const int N = in_sizes[0] / 3;
    const int block = 256;
    const int grid = (N + block - 1) / block;
    deformnet_kernel<<<grid, block, 0, stream>>>(x, e, tables, W1, b1, W2, b2,
                                                 W3, b3, bb, out, N);
}